// Round 5
// baseline (1466.526 us; speedup 1.0000x reference)
//
#include <hip/hip_runtime.h>
#include <hip/hip_bf16.h>
#include <stdint.h>

#define DF   256
#define NBAS 30
#define RREL 64
#define NLAY 3
#define EPSBN 1e-5f

typedef short  bf16x8 __attribute__((ext_vector_type(8)));
typedef float  f32x4  __attribute__((ext_vector_type(4)));
typedef ushort u16x4  __attribute__((ext_vector_type(4)));

typedef __attribute__((address_space(1))) const unsigned int gu32;
typedef __attribute__((address_space(3))) unsigned int       lu32;

__device__ __forceinline__ void gload16(const void* g, void* l){
  __builtin_amdgcn_global_load_lds((gu32*)g, (lu32*)l, 16, 0, 0);
}

__device__ __forceinline__ ushort f2bf(float f){
  union { float f; uint32_t u; } v; v.f = f;
  uint32_t r = (v.u + 0x7FFFu + ((v.u >> 16) & 1u)) >> 16;
  return (ushort)r;
}

// ---------------- counting sort by relation (64 bins) ----------------
__global__ __launch_bounds__(256) void k_hist_rel(const int* __restrict__ et,
                                                  int* __restrict__ counts, int E){
  __shared__ int lh[RREL];
  int t = threadIdx.x;
  if (t < RREL) lh[t] = 0;
  __syncthreads();
  int i = blockIdx.x*256 + t;
  if (i < E) atomicAdd(&lh[et[i]], 1);
  __syncthreads();
  if (t < RREL && lh[t]) atomicAdd(&counts[t], lh[t]);
}

__global__ void k_scan_rel(const int* __restrict__ counts,
                           int* __restrict__ relOff, int* __restrict__ tileOff){
  int l = threadIdx.x;          // 64 lanes
  int c  = counts[l];
  int tt = (c + 127) >> 7;
  int ic = c, it = tt;
  #pragma unroll
  for (int o = 1; o < 64; o <<= 1){
    int u = __shfl_up(ic, o); if (l >= o) ic += u;
    int v = __shfl_up(it, o); if (l >= o) it += v;
  }
  if (l == 0){ relOff[0] = 0; tileOff[0] = 0; }
  relOff[l+1]  = ic;
  tileOff[l+1] = it;
}

__global__ __launch_bounds__(256) void k_place_rel(const int* __restrict__ et,
    const int* __restrict__ src, const int* __restrict__ dst,
    const float* __restrict__ nrm, const int* __restrict__ relOff,
    int* __restrict__ cursor, int* __restrict__ srcR, int* __restrict__ dstR,
    float* __restrict__ nrmR, int E){
  __shared__ int lcnt[RREL];
  __shared__ int lbase[RREL];
  int t = threadIdx.x;
  if (t < RREL) lcnt[t] = 0;
  __syncthreads();
  int i = blockIdx.x*256 + t;
  int r = 0, my = 0;
  bool v = (i < E);
  if (v){ r = et[i]; my = atomicAdd(&lcnt[r], 1); }
  __syncthreads();
  if (t < RREL && lcnt[t]) lbase[t] = atomicAdd(&cursor[t], lcnt[t]);
  __syncthreads();
  if (v){
    int p = relOff[r] + lbase[r] + my;
    srcR[p] = src[i];
    dstR[p] = dst[i];
    nrmR[p] = nrm[i];
  }
}

// ---------------- W_rel precompute: Wt[l][r][col][k] = bf16(sum_b comp*V) ----------------
__global__ __launch_bounds__(256) void k_wrel(const float* __restrict__ V,
    const float* __restrict__ comp, ushort* __restrict__ Wt){
  const int r  = blockIdx.x;
  const int k0 = blockIdx.y*32;
  const int l  = blockIdx.z;
  const int col = threadIdx.x;
  float acc[32];
  #pragma unroll
  for (int kk = 0; kk < 32; ++kk) acc[kk] = 0.f;
  for (int b = 0; b < NBAS; ++b){
    float cb = comp[(size_t)(l*RREL + r)*NBAS + b];
    const float* Vb = V + (((size_t)(l*NBAS + b)*DF) + k0)*DF + col;
    #pragma unroll
    for (int kk = 0; kk < 32; ++kk) acc[kk] = fmaf(cb, Vb[(size_t)kk*DF], acc[kk]);
  }
  ushort* o = Wt + ((size_t)(l*RREL + r)*DF + col)*DF + k0;
  #pragma unroll
  for (int i4 = 0; i4 < 8; ++i4){
    u16x4 p;
    #pragma unroll
    for (int j = 0; j < 4; ++j) p[j] = f2bf(acc[i4*4 + j]);
    *(u16x4*)(o + i4*4) = p;
  }
}

// ---------------- transpose fp32 [K,256] -> bf16 [256,K], layered via z ----------------
__global__ void k_transpose_bf16(const float* __restrict__ in, ushort* __restrict__ out, int K){
  const float* inz  = in  + (size_t)blockIdx.z*K*DF;
  ushort*      outz = out + (size_t)blockIdx.z*DF*K;
  __shared__ float tile[32][33];
  int k0 = blockIdx.x*32, n0 = blockIdx.y*32;
  int tx = threadIdx.x & 31, ty = threadIdx.x >> 5;
  #pragma unroll
  for (int i = 0; i < 32; i += 8)
    tile[ty+i][tx] = inz[(size_t)(k0+ty+i)*DF + n0 + tx];
  __syncthreads();
  #pragma unroll
  for (int i = 0; i < 32; i += 8)
    outz[(size_t)(n0+ty+i)*K + k0 + tx] = f2bf(tile[tx][ty+i]);
}

// ---------------- fp32 -> bf16 ----------------
__global__ __launch_bounds__(256) void k_f2b(const float* __restrict__ in,
                                             ushort* __restrict__ o){
  size_t i = ((size_t)blockIdx.x*256 + threadIdx.x)*4;
  f32x4 v = *(const f32x4*)(in + i);
  u16x4 p;
  #pragma unroll
  for (int j = 0; j < 4; ++j) p[j] = f2bf(v[j]);
  *(u16x4*)(o + i) = p;
}

// ---------------- edge GEMM: per-relation [128 edges x 256] @ W_r, atomic scatter ----------------
__global__ __launch_bounds__(512) void k_edge_gemm(
    const ushort* __restrict__ xh, const ushort* __restrict__ Wt,
    const int* __restrict__ srcR, const int* __restrict__ dstR,
    const float* __restrict__ nrmR, const int* __restrict__ relOff,
    const int* __restrict__ tileOff, float* __restrict__ agg){
  __shared__ __align__(16) ushort As[128*64];   // 16 KB
  __shared__ __align__(16) ushort Bs[256*64];   // 32 KB
  const int b = blockIdx.x;
  if (b >= tileOff[RREL]) return;
  // find relation r: tileOff[r] <= b < tileOff[r+1]
  int r = 0;
  #pragma unroll
  for (int step = 32; step; step >>= 1)
    if (r + step <= RREL-1 && tileOff[r + step] <= b) r += step;
  const int eb   = relOff[r] + (b - tileOff[r])*128;
  const int emax = relOff[r+1] - 1;
  const int rows = min(128, relOff[r+1] - eb);

  const int tid  = threadIdx.x;
  const int lane = tid & 63, wid = tid >> 6;
  const int wr = (wid >> 2)*64, wc = (wid & 3)*64;
  const int l15 = lane & 15, lhi = lane >> 4;
  const int ko = (tid & 7)*8;

  // preload gather addresses (loop-invariant over kt)
  const ushort* pa[2];
  #pragma unroll
  for (int i = 0; i < 2; ++i){
    int e = eb + ((tid + i*512) >> 3);
    if (e > emax) e = emax;
    pa[i] = xh + (size_t)srcR[e]*DF + ko;
  }
  const ushort* Bt = Wt + (size_t)r*DF*DF;
  const ushort* pb[4];
  #pragma unroll
  for (int i = 0; i < 4; ++i)
    pb[i] = Bt + (size_t)((tid >> 3) + i*64)*DF + ko;

  const f32x4 z = {0.f, 0.f, 0.f, 0.f};
  f32x4 acc[4][4];
  #pragma unroll
  for (int m = 0; m < 4; ++m)
    #pragma unroll
    for (int n = 0; n < 4; ++n) acc[m][n] = z;

  for (int kt = 0; kt < 4; ++kt){
    const int kbase = kt*64;
    __syncthreads();
    #pragma unroll
    for (int i = 0; i < 2; ++i) gload16(pa[i] + kbase, As + (tid + i*512)*8);
    #pragma unroll
    for (int i = 0; i < 4; ++i) gload16(pb[i] + kbase, Bs + (tid + i*512)*8);
    __syncthreads();
    #pragma unroll
    for (int ks = 0; ks < 2; ++ks){
      const int kb = ks*32 + lhi*8;
      bf16x8 af[4], bfr[4];
      #pragma unroll
      for (int m = 0; m < 4; ++m) af[m]  = *(const bf16x8*)(As + (wr + m*16 + l15)*64 + kb);
      #pragma unroll
      for (int n = 0; n < 4; ++n) bfr[n] = *(const bf16x8*)(Bs + (wc + n*16 + l15)*64 + kb);
      #pragma unroll
      for (int m = 0; m < 4; ++m)
        #pragma unroll
        for (int n = 0; n < 4; ++n)
          acc[m][n] = __builtin_amdgcn_mfma_f32_16x16x32_bf16(af[m], bfr[n], acc[m][n], 0, 0, 0);
    }
  }

  // epilogue: scale by norm, atomic scatter to agg[dst]
  #pragma unroll
  for (int m = 0; m < 4; ++m){
    int   dloc[4];
    float wloc[4];
    #pragma unroll
    for (int q = 0; q < 4; ++q){
      int lr = wr + m*16 + lhi*4 + q;
      int e  = eb + lr;
      bool val = (lr < rows);
      int ec = val ? e : emax;
      wloc[q] = val ? nrmR[ec] : 0.f;
      dloc[q] = dstR[ec];
    }
    #pragma unroll
    for (int n = 0; n < 4; ++n){
      int col = wc + n*16 + l15;
      #pragma unroll
      for (int q = 0; q < 4; ++q)
        atomicAdd(&agg[(size_t)dloc[q]*DF + col], acc[m][n][q]*wloc[q]);
    }
  }
}

// ---------------- agg + bias -> bf16 ----------------
__global__ __launch_bounds__(256) void k_addbias(const float* __restrict__ y,
    const float* __restrict__ bias, ushort* __restrict__ xb){
  size_t i = ((size_t)blockIdx.x*256 + threadIdx.x)*4;
  int col = (int)(i & (DF-1));
  f32x4 v  = *(const f32x4*)(y + i);
  f32x4 bv = *(const f32x4*)(bias + col);
  u16x4 o;
  #pragma unroll
  for (int j = 0; j < 4; ++j) o[j] = f2bf(v[j] + bv[j]);
  *(u16x4*)(xb + i) = o;
}

// ---------------- MLP GEMM (K=256): y = A @ Bt + bias, fused BN stats ----------------
__global__ __launch_bounds__(256) void k_gemm_mlp(
    const ushort* __restrict__ A, const ushort* __restrict__ Bt,
    const float* __restrict__ bias, float* __restrict__ out,
    float* __restrict__ msum, float* __restrict__ ssum, int a_valid){
  __shared__ __align__(16) ushort As[128*64];
  __shared__ __align__(16) ushort Bs[128*64];
  const int tid  = threadIdx.x;
  const int brow = blockIdx.x*128;
  const int bcol = blockIdx.y*128;
  const int lane = tid & 63, wid = tid >> 6;
  const int wr = (wid >> 1)*64, wc = (wid & 1)*64;
  const int l15 = lane & 15, lhi = lane >> 4;

  const f32x4 z = {0.f, 0.f, 0.f, 0.f};
  f32x4 acc[4][4];
  #pragma unroll
  for (int m = 0; m < 4; ++m)
    #pragma unroll
    for (int n = 0; n < 4; ++n) acc[m][n] = z;

  for (int kt = 0; kt < 4; ++kt){
    const int kbase = kt*64;
    __syncthreads();
    #pragma unroll
    for (int i = 0; i < 4; ++i){
      int c   = tid + i*256;
      int row = c >> 3, ko = (c & 7)*8;
      int ra  = brow + row; if (ra >= a_valid) ra = a_valid - 1;
      gload16(A  + (size_t)ra*DF + kbase + ko,           As + c*8);
      gload16(Bt + (size_t)(bcol + row)*DF + kbase + ko, Bs + c*8);
    }
    __syncthreads();
    #pragma unroll
    for (int ks = 0; ks < 2; ++ks){
      const int kb = ks*32 + lhi*8;
      bf16x8 af[4], bfr[4];
      #pragma unroll
      for (int m = 0; m < 4; ++m) af[m]  = *(const bf16x8*)(As + (wr + m*16 + l15)*64 + kb);
      #pragma unroll
      for (int n = 0; n < 4; ++n) bfr[n] = *(const bf16x8*)(Bs + (wc + n*16 + l15)*64 + kb);
      #pragma unroll
      for (int m = 0; m < 4; ++m)
        #pragma unroll
        for (int n = 0; n < 4; ++n)
          acc[m][n] = __builtin_amdgcn_mfma_f32_16x16x32_bf16(af[m], bfr[n], acc[m][n], 0, 0, 0);
    }
  }

  #pragma unroll
  for (int n = 0; n < 4; ++n){
    const int col = bcol + wc + n*16 + l15;
    const float bv = bias[col];
    float s = 0.f, s2 = 0.f;
    #pragma unroll
    for (int m = 0; m < 4; ++m){
      #pragma unroll
      for (int r = 0; r < 4; ++r){
        int grow = brow + wr + m*16 + lhi*4 + r;
        float v  = acc[m][n][r] + bv;
        out[(size_t)grow*DF + col] = v;
        if (grow < a_valid){ s += v; s2 = fmaf(v, v, s2); }
      }
    }
    s  += __shfl_xor(s, 16);  s  += __shfl_xor(s, 32);
    s2 += __shfl_xor(s2, 16); s2 += __shfl_xor(s2, 32);
    if (lhi == 0){ atomicAdd(&msum[col], s); atomicAdd(&ssum[col], s2); }
  }
}

// ---------------- BN apply + ReLU ----------------
// OM=0: write bf16 xb only; OM=1: write fp32 out + bf16 xh
template<int OM>
__global__ __launch_bounds__(256) void k_bn_apply(const float* __restrict__ y,
    const float* __restrict__ msum, const float* __restrict__ ssum,
    const float* __restrict__ g, const float* __restrict__ bt,
    float inv_n, float* __restrict__ of, ushort* __restrict__ ob,
    ushort* __restrict__ oh){
  size_t i = ((size_t)blockIdx.x*256 + threadIdx.x)*4;
  int col = (int)(i & (DF-1));
  f32x4 v   = *(const f32x4*)(y + i);
  f32x4 mu_ = *(const f32x4*)(msum + col);
  f32x4 s2_ = *(const f32x4*)(ssum + col);
  f32x4 g_  = *(const f32x4*)(g + col);
  f32x4 b_  = *(const f32x4*)(bt + col);
  u16x4 hb; f32x4 vf;
  #pragma unroll
  for (int j = 0; j < 4; ++j){
    float mu  = mu_[j]*inv_n;
    float var = s2_[j]*inv_n - mu*mu;
    float sc  = g_[j]*rsqrtf(var + EPSBN);
    float val = fmaxf(0.f, fmaf(v[j] - mu, sc, b_[j]));
    vf[j] = val;
    hb[j] = f2bf(val);
  }
  if (OM == 0){
    *(u16x4*)(ob + i) = hb;
  } else {
    *(f32x4*)(of + i) = vf;
    *(u16x4*)(oh + i) = hb;
  }
}

// ---------------- launch ----------------
extern "C" void kernel_launch(void* const* d_in, const int* in_sizes, int n_in,
                              void* d_out, int out_size, void* d_ws, size_t ws_size,
                              hipStream_t stream){
  const float* h0   = (const float*)d_in[0];
  const float* norm = (const float*)d_in[1];
  const float* V    = (const float*)d_in[2];
  const float* comp = (const float*)d_in[3];
  const float* bias = (const float*)d_in[4];
  const float* W1   = (const float*)d_in[5];
  const float* b1   = (const float*)d_in[6];
  const float* g1   = (const float*)d_in[7];
  const float* bt1  = (const float*)d_in[8];
  const float* W2   = (const float*)d_in[9];
  const float* b2   = (const float*)d_in[10];
  const float* g2   = (const float*)d_in[11];
  const float* bt2  = (const float*)d_in[12];
  const int* src    = (const int*)d_in[13];
  const int* dst    = (const int*)d_in[14];
  const int* et     = (const int*)d_in[15];

  const int N  = in_sizes[0] / DF;     // 20000
  const int E  = in_sizes[13];         // 320000
  const int MT = (N + 127) / 128;      // 157
  const int MP = MT * 128;             // 20096
  const size_t MPDF = (size_t)MP * DF;
  const size_t NDF  = (size_t)N * DF;
  const int NTILES = (E + 127)/128 + RREL;
  float* out = (float*)d_out;

  uint8_t* w = (uint8_t*)d_ws;
  size_t o = 0;
  auto carve = [&](size_t bytes)->void*{
    void* p = w + o;
    o = (o + bytes + 511) & ~(size_t)511;
    return p;
  };
  float*  y       = (float*) carve(MPDF*4);                       // agg / MLP out
  ushort* xb      = (ushort*)carve(MPDF*2);                       // MLP bf16 input
  ushort* xh      = (ushort*)carve(NDF*2);                        // h bf16 (per layer)
  ushort* Wt      = (ushort*)carve((size_t)NLAY*RREL*DF*DF*2);    // combined rel weights^T
  ushort* W1t     = (ushort*)carve((size_t)NLAY*DF*DF*2);
  ushort* W2t     = (ushort*)carve((size_t)NLAY*DF*DF*2);
  float*  bnacc   = (float*) carve((size_t)NLAY*4*DF*4);
  int*    counts  = (int*)   carve(RREL*4);
  int*    cursor  = (int*)   carve(RREL*4);
  int*    relOff  = (int*)   carve((RREL+1)*4);
  int*    tileOff = (int*)   carve((RREL+1)*4);
  int*    srcR    = (int*)   carve((size_t)E*4);
  int*    dstR    = (int*)   carve((size_t)E*4);
  float*  nrmR    = (float*) carve((size_t)E*4);

  hipMemsetAsync(counts, 0, RREL*4, stream);
  hipMemsetAsync(cursor, 0, RREL*4, stream);
  hipMemsetAsync(bnacc, 0, (size_t)NLAY*4*DF*4, stream);

  // relation sort
  k_hist_rel <<<(E+255)/256, 256, 0, stream>>>(et, counts, E);
  k_scan_rel <<<1, 64, 0, stream>>>(counts, relOff, tileOff);
  k_place_rel<<<(E+255)/256, 256, 0, stream>>>(et, src, dst, norm, relOff, cursor,
                                               srcR, dstR, nrmR, E);

  // reps[0] = h ; xh = bf16(h)
  hipMemcpyAsync(out, h0, NDF*4, hipMemcpyDeviceToDevice, stream);
  k_f2b<<<(int)(NDF/1024), 256, 0, stream>>>(h0, xh);

  // weights
  k_wrel<<<dim3(RREL, DF/32, NLAY), 256, 0, stream>>>(V, comp, Wt);
  k_transpose_bf16<<<dim3(DF/32, DF/32, NLAY), 256, 0, stream>>>(W1, W1t, DF);
  k_transpose_bf16<<<dim3(DF/32, DF/32, NLAY), 256, 0, stream>>>(W2, W2t, DF);

  const float inv_n = 1.f / (float)N;
  for (int l = 0; l < NLAY; ++l){
    float* ms1 = bnacc + (size_t)(l*4 + 0)*DF;
    float* ss1 = bnacc + (size_t)(l*4 + 1)*DF;
    float* ms2 = bnacc + (size_t)(l*4 + 2)*DF;
    float* ss2 = bnacc + (size_t)(l*4 + 3)*DF;

    hipMemsetAsync(y, 0, NDF*4, stream);
    k_edge_gemm<<<NTILES, 512, 0, stream>>>(xh, Wt + (size_t)l*RREL*DF*DF,
                                            srcR, dstR, nrmR, relOff, tileOff, y);
    k_addbias<<<(int)(NDF/1024), 256, 0, stream>>>(y, bias + (size_t)l*DF, xb);

    k_gemm_mlp<<<dim3(MT, 2), 256, 0, stream>>>(xb, W1t + (size_t)l*DF*DF,
                                                b1 + (size_t)l*DF, y, ms1, ss1, N);
    k_bn_apply<0><<<(int)(NDF/1024), 256, 0, stream>>>(
        y, ms1, ss1, g1 + (size_t)l*DF, bt1 + (size_t)l*DF, inv_n, nullptr, xb, nullptr);

    k_gemm_mlp<<<dim3(MT, 2), 256, 0, stream>>>(xb, W2t + (size_t)l*DF*DF,
                                                b2 + (size_t)l*DF, y, ms2, ss2, N);
    k_bn_apply<1><<<(int)(NDF/1024), 256, 0, stream>>>(
        y, ms2, ss2, g2 + (size_t)l*DF, bt2 + (size_t)l*DF, inv_n,
        out + (size_t)(l+1)*NDF, nullptr, xh);
  }
}

// Round 7
// 1053.366 us; speedup vs baseline: 1.3922x; 1.3922x over previous
//
#include <hip/hip_runtime.h>
#include <hip/hip_bf16.h>
#include <stdint.h>

#define DF   256
#define NBAS 30
#define RREL 64
#define NLAY 3
#define EPSBN 1e-5f

typedef short  bf16x8 __attribute__((ext_vector_type(8)));
typedef float  f32x4  __attribute__((ext_vector_type(4)));
typedef ushort u16x4  __attribute__((ext_vector_type(4)));

typedef __attribute__((address_space(1))) const unsigned int gu32;
typedef __attribute__((address_space(3))) unsigned int       lu32;

__device__ __forceinline__ void gload16(const void* g, void* l){
  __builtin_amdgcn_global_load_lds((gu32*)g, (lu32*)l, 16, 0, 0);
}

__device__ __forceinline__ ushort f2bf(float f){
  union { float f; uint32_t u; } v; v.f = f;
  uint32_t r = (v.u + 0x7FFFu + ((v.u >> 16) & 1u)) >> 16;
  return (ushort)r;
}
__device__ __forceinline__ float bf2f(ushort u){
  union { uint32_t u; float f; } v; v.u = (uint32_t)u << 16;
  return v.f;
}

// ---------------- histograms ----------------
__global__ __launch_bounds__(256) void k_hist_rel(const int* __restrict__ et,
                                                  int* __restrict__ counts, int E){
  __shared__ int lh[RREL];
  int t = threadIdx.x;
  if (t < RREL) lh[t] = 0;
  __syncthreads();
  int i = blockIdx.x*256 + t;
  if (i < E) atomicAdd(&lh[et[i]], 1);
  __syncthreads();
  if (t < RREL && lh[t]) atomicAdd(&counts[t], lh[t]);
}

__global__ void k_hist_dst(const int* __restrict__ dst, int* __restrict__ counts, int E){
  int i = blockIdx.x*blockDim.x + threadIdx.x;
  if (i < E) atomicAdd(&counts[dst[i]], 1);
}

// ---------------- scans ----------------
__global__ void k_scan_rel(const int* __restrict__ counts,
                           int* __restrict__ relOff, int* __restrict__ tileOff){
  int l = threadIdx.x;          // 64 lanes
  int c  = counts[l];
  int tt = (c + 127) >> 7;
  int ic = c, it = tt;
  #pragma unroll
  for (int o = 1; o < 64; o <<= 1){
    int u = __shfl_up(ic, o); if (l >= o) ic += u;
    int v = __shfl_up(it, o); if (l >= o) it += v;
  }
  if (l == 0){ relOff[0] = 0; tileOff[0] = 0; }
  relOff[l+1]  = ic;
  tileOff[l+1] = it;
}

__global__ void k_scan_dst(const int* __restrict__ counts, int* __restrict__ offs, int n){
  __shared__ int tmp[1024];
  __shared__ int carry;
  int t = threadIdx.x;
  if (t == 0) carry = 0;
  __syncthreads();
  for (int s = 0; s < n; s += 1024){
    int i = s + t;
    int v = (i < n) ? counts[i] : 0;
    tmp[t] = v;
    __syncthreads();
    for (int o = 1; o < 1024; o <<= 1){
      int u = (t >= o) ? tmp[t - o] : 0;
      __syncthreads();
      tmp[t] += u;
      __syncthreads();
    }
    int incl = tmp[t];
    int base = carry;
    if (i < n) offs[i] = base + incl - v;
    __syncthreads();
    if (t == 1023) carry = base + incl;
    __syncthreads();
  }
  if (t == 0) offs[n] = carry;
}

// ---------------- placements ----------------
__global__ __launch_bounds__(256) void k_place_rel(const int* __restrict__ et,
    const int* __restrict__ src, const int* __restrict__ relOff,
    int* __restrict__ cursor, int* __restrict__ srcR, int* __restrict__ posR, int E){
  __shared__ int lcnt[RREL];
  __shared__ int lbase[RREL];
  int t = threadIdx.x;
  if (t < RREL) lcnt[t] = 0;
  __syncthreads();
  int i = blockIdx.x*256 + t;
  int r = 0, my = 0;
  bool v = (i < E);
  if (v){ r = et[i]; my = atomicAdd(&lcnt[r], 1); }
  __syncthreads();
  if (t < RREL && lcnt[t]) lbase[t] = atomicAdd(&cursor[t], lcnt[t]);
  __syncthreads();
  if (v){
    int p = relOff[r] + lbase[r] + my;
    srcR[p] = src[i];
    posR[i] = p;
  }
}

__global__ __launch_bounds__(256) void k_place_dst(const int* __restrict__ dst,
    const int* __restrict__ offsD, int* __restrict__ cursorD,
    const int* __restrict__ posR, const float* __restrict__ nrm,
    int* __restrict__ dstPos, float* __restrict__ nrmD, int E){
  int i = blockIdx.x*256 + threadIdx.x;
  if (i < E){
    int d = dst[i];
    int q = offsD[d] + atomicAdd(&cursorD[d], 1);
    dstPos[posR[i]] = q;
    nrmD[q] = nrm[i];
  }
}

// ---------------- W_rel precompute: Wt[l][r][col][k] = bf16(sum_b comp*V) ----------------
__global__ __launch_bounds__(256) void k_wrel(const float* __restrict__ V,
    const float* __restrict__ comp, ushort* __restrict__ Wt){
  const int r  = blockIdx.x;
  const int k0 = blockIdx.y*32;
  const int l  = blockIdx.z;
  const int col = threadIdx.x;
  float acc[32];
  #pragma unroll
  for (int kk = 0; kk < 32; ++kk) acc[kk] = 0.f;
  for (int b = 0; b < NBAS; ++b){
    float cb = comp[(size_t)(l*RREL + r)*NBAS + b];
    const float* Vb = V + (((size_t)(l*NBAS + b)*DF) + k0)*DF + col;
    #pragma unroll
    for (int kk = 0; kk < 32; ++kk) acc[kk] = fmaf(cb, Vb[(size_t)kk*DF], acc[kk]);
  }
  ushort* o = Wt + ((size_t)(l*RREL + r)*DF + col)*DF + k0;
  #pragma unroll
  for (int i4 = 0; i4 < 8; ++i4){
    u16x4 p;
    #pragma unroll
    for (int j = 0; j < 4; ++j) p[j] = f2bf(acc[i4*4 + j]);
    *(u16x4*)(o + i4*4) = p;
  }
}

// ---------------- transpose fp32 [K,256] -> bf16 [256,K], layered via z ----------------
__global__ void k_transpose_bf16(const float* __restrict__ in, ushort* __restrict__ out, int K){
  const float* inz  = in  + (size_t)blockIdx.z*K*DF;
  ushort*      outz = out + (size_t)blockIdx.z*DF*K;
  __shared__ float tile[32][33];
  int k0 = blockIdx.x*32, n0 = blockIdx.y*32;
  int tx = threadIdx.x & 31, ty = threadIdx.x >> 5;
  #pragma unroll
  for (int i = 0; i < 32; i += 8)
    tile[ty+i][tx] = inz[(size_t)(k0+ty+i)*DF + n0 + tx];
  __syncthreads();
  #pragma unroll
  for (int i = 0; i < 32; i += 8)
    outz[(size_t)(n0+ty+i)*K + k0 + tx] = f2bf(tile[tx][ty+i]);
}

// ---------------- fp32 -> bf16 ----------------
__global__ __launch_bounds__(256) void k_f2b(const float* __restrict__ in,
                                             ushort* __restrict__ o){
  size_t i = ((size_t)blockIdx.x*256 + threadIdx.x)*4;
  f32x4 v = *(const f32x4*)(in + i);
  u16x4 p;
  #pragma unroll
  for (int j = 0; j < 4; ++j) p[j] = f2bf(v[j]);
  *(u16x4*)(o + i) = p;
}

// ---------------- edge GEMM: [128 edges x 256] @ W_r -> m rows at dst-sorted slots ----------------
__global__ __launch_bounds__(512) void k_edge_gemm(
    const ushort* __restrict__ xh, const ushort* __restrict__ Wt,
    const int* __restrict__ srcR, const int* __restrict__ dstPos,
    const int* __restrict__ relOff, const int* __restrict__ tileOff,
    ushort* __restrict__ mD){
  __shared__ __align__(16) ushort As[128*64];   // 16 KB
  __shared__ __align__(16) ushort Bs[256*64];   // 32 KB
  const int b = blockIdx.x;
  if (b >= tileOff[RREL]) return;
  int r = 0;
  #pragma unroll
  for (int step = 32; step; step >>= 1)
    if (r + step <= RREL-1 && tileOff[r + step] <= b) r += step;
  const int eb   = relOff[r] + (b - tileOff[r])*128;
  const int emax = relOff[r+1] - 1;
  const int rows = min(128, relOff[r+1] - eb);

  const int tid  = threadIdx.x;
  const int lane = tid & 63, wid = tid >> 6;
  const int wr = (wid >> 2)*64, wc = (wid & 3)*64;
  const int l15 = lane & 15, lhi = lane >> 4;
  const int ko = (tid & 7)*8;

  const ushort* pa[2];
  #pragma unroll
  for (int i = 0; i < 2; ++i){
    int e = eb + ((tid + i*512) >> 3);
    if (e > emax) e = emax;
    pa[i] = xh + (size_t)srcR[e]*DF + ko;
  }
  const ushort* Bt = Wt + (size_t)r*DF*DF;
  const ushort* pb[4];
  #pragma unroll
  for (int i = 0; i < 4; ++i)
    pb[i] = Bt + (size_t)((tid >> 3) + i*64)*DF + ko;

  const f32x4 z = {0.f, 0.f, 0.f, 0.f};
  f32x4 acc[4][4];
  #pragma unroll
  for (int m = 0; m < 4; ++m)
    #pragma unroll
    for (int n = 0; n < 4; ++n) acc[m][n] = z;

  for (int kt = 0; kt < 4; ++kt){
    const int kbase = kt*64;
    __syncthreads();
    #pragma unroll
    for (int i = 0; i < 2; ++i) gload16(pa[i] + kbase, As + (tid + i*512)*8);
    #pragma unroll
    for (int i = 0; i < 4; ++i) gload16(pb[i] + kbase, Bs + (tid + i*512)*8);
    __syncthreads();
    #pragma unroll
    for (int ks = 0; ks < 2; ++ks){
      const int kb = ks*32 + lhi*8;
      bf16x8 af[4], bfr[4];
      #pragma unroll
      for (int m = 0; m < 4; ++m) af[m]  = *(const bf16x8*)(As + (wr + m*16 + l15)*64 + kb);
      #pragma unroll
      for (int n = 0; n < 4; ++n) bfr[n] = *(const bf16x8*)(Bs + (wc + n*16 + l15)*64 + kb);
      #pragma unroll
      for (int m = 0; m < 4; ++m)
        #pragma unroll
        for (int n = 0; n < 4; ++n)
          acc[m][n] = __builtin_amdgcn_mfma_f32_16x16x32_bf16(af[m], bfr[n], acc[m][n], 0, 0, 0);
    }
  }

  // epilogue: stage bf16 rows in LDS (two 64-row halves in Bs), burst 512B rows to dst slot
  #pragma unroll
  for (int half = 0; half < 2; ++half){
    __syncthreads();
    if ((wid >> 2) == half){
      #pragma unroll
      for (int m = 0; m < 4; ++m)
        #pragma unroll
        for (int q = 0; q < 4; ++q){
          int rl = m*16 + lhi*4 + q;   // local row within half
          #pragma unroll
          for (int n = 0; n < 4; ++n)
            Bs[rl*256 + wc + n*16 + l15] = f2bf(acc[m][n][q]);
        }
    }
    __syncthreads();
    int row = tid >> 3;                // 0..63
    int gr  = half*64 + row;           // tile-local edge row
    if (gr < rows){
      int q = dstPos[eb + gr];
      const uint4* s = (const uint4*)((const char*)Bs + tid*64);
      uint4* d = (uint4*)((char*)(mD + (size_t)q*DF) + (tid & 7)*64);
      #pragma unroll
      for (int i = 0; i < 4; ++i) d[i] = s[i];
    }
  }
}

// ---------------- segment sum over dst-sorted m + bias -> bf16 xb ----------------
__global__ __launch_bounds__(256) void k_seg_sum(
    const ushort* __restrict__ mD, const float* __restrict__ nrmD,
    const int* __restrict__ offsD, const float* __restrict__ bias,
    ushort* __restrict__ xb, int N){
  const int w = blockIdx.x*4 + (threadIdx.x >> 6);
  if (w >= N) return;
  const int lane = threadIdx.x & 63;
  const int beg = offsD[w], end = offsD[w+1];
  f32x4 a0 = {0.f,0.f,0.f,0.f}, a1 = {0.f,0.f,0.f,0.f};
  const ushort* p = mD + (size_t)beg*DF + lane*4;
  int j = beg;
  for (; j + 2 <= end; j += 2, p += 2*DF){
    u16x4 v0 = *(const u16x4*)(p);
    u16x4 v1 = *(const u16x4*)(p + DF);
    float n0 = nrmD[j], n1 = nrmD[j+1];
    #pragma unroll
    for (int t = 0; t < 4; ++t){
      a0[t] = fmaf(n0, bf2f(v0[t]), a0[t]);
      a1[t] = fmaf(n1, bf2f(v1[t]), a1[t]);
    }
  }
  if (j < end){
    u16x4 v0 = *(const u16x4*)(p);
    float n0 = nrmD[j];
    #pragma unroll
    for (int t = 0; t < 4; ++t) a0[t] = fmaf(n0, bf2f(v0[t]), a0[t]);
  }
  f32x4 bv = *(const f32x4*)(bias + lane*4);
  u16x4 o;
  #pragma unroll
  for (int t = 0; t < 4; ++t) o[t] = f2bf(a0[t] + a1[t] + bv[t]);
  *(u16x4*)(xb + (size_t)w*DF + lane*4) = o;
}

// ---------------- MLP GEMM (K=256): y = A @ Bt + bias, fused BN stats ----------------
__global__ __launch_bounds__(256) void k_gemm_mlp(
    const ushort* __restrict__ A, const ushort* __restrict__ Bt,
    const float* __restrict__ bias, float* __restrict__ out,
    float* __restrict__ msum, float* __restrict__ ssum, int a_valid){
  __shared__ __align__(16) ushort As[128*64];
  __shared__ __align__(16) ushort Bs[128*64];
  const int tid  = threadIdx.x;
  const int brow = blockIdx.x*128;
  const int bcol = blockIdx.y*128;
  const int lane = tid & 63, wid = tid >> 6;
  const int wr = (wid >> 1)*64, wc = (wid & 1)*64;
  const int l15 = lane & 15, lhi = lane >> 4;

  const f32x4 z = {0.f, 0.f, 0.f, 0.f};
  f32x4 acc[4][4];
  #pragma unroll
  for (int m = 0; m < 4; ++m)
    #pragma unroll
    for (int n = 0; n < 4; ++n) acc[m][n] = z;

  for (int kt = 0; kt < 4; ++kt){
    const int kbase = kt*64;
    __syncthreads();
    #pragma unroll
    for (int i = 0; i < 4; ++i){
      int c   = tid + i*256;
      int row = c >> 3, ko = (c & 7)*8;
      int ra  = brow + row; if (ra >= a_valid) ra = a_valid - 1;
      gload16(A  + (size_t)ra*DF + kbase + ko,           As + c*8);
      gload16(Bt + (size_t)(bcol + row)*DF + kbase + ko, Bs + c*8);
    }
    __syncthreads();
    #pragma unroll
    for (int ks = 0; ks < 2; ++ks){
      const int kb = ks*32 + lhi*8;
      bf16x8 af[4], bfr[4];
      #pragma unroll
      for (int m = 0; m < 4; ++m) af[m]  = *(const bf16x8*)(As + (wr + m*16 + l15)*64 + kb);
      #pragma unroll
      for (int n = 0; n < 4; ++n) bfr[n] = *(const bf16x8*)(Bs + (wc + n*16 + l15)*64 + kb);
      #pragma unroll
      for (int m = 0; m < 4; ++m)
        #pragma unroll
        for (int n = 0; n < 4; ++n)
          acc[m][n] = __builtin_amdgcn_mfma_f32_16x16x32_bf16(af[m], bfr[n], acc[m][n], 0, 0, 0);
    }
  }

  #pragma unroll
  for (int n = 0; n < 4; ++n){
    const int col = bcol + wc + n*16 + l15;
    const float bv = bias[col];
    float s = 0.f, s2 = 0.f;
    #pragma unroll
    for (int m = 0; m < 4; ++m){
      #pragma unroll
      for (int r = 0; r < 4; ++r){
        int grow = brow + wr + m*16 + lhi*4 + r;
        float v  = acc[m][n][r] + bv;
        out[(size_t)grow*DF + col] = v;
        if (grow < a_valid){ s += v; s2 = fmaf(v, v, s2); }
      }
    }
    s  += __shfl_xor(s, 16);  s  += __shfl_xor(s, 32);
    s2 += __shfl_xor(s2, 16); s2 += __shfl_xor(s2, 32);
    if (lhi == 0){ atomicAdd(&msum[col], s); atomicAdd(&ssum[col], s2); }
  }
}

// ---------------- BN apply + ReLU ----------------
template<int OM>
__global__ __launch_bounds__(256) void k_bn_apply(const float* __restrict__ y,
    const float* __restrict__ msum, const float* __restrict__ ssum,
    const float* __restrict__ g, const float* __restrict__ bt,
    float inv_n, float* __restrict__ of, ushort* __restrict__ ob,
    ushort* __restrict__ oh){
  size_t i = ((size_t)blockIdx.x*256 + threadIdx.x)*4;
  int col = (int)(i & (DF-1));
  f32x4 v   = *(const f32x4*)(y + i);
  f32x4 mu_ = *(const f32x4*)(msum + col);
  f32x4 s2_ = *(const f32x4*)(ssum + col);
  f32x4 g_  = *(const f32x4*)(g + col);
  f32x4 b_  = *(const f32x4*)(bt + col);
  u16x4 hb; f32x4 vf;
  #pragma unroll
  for (int j = 0; j < 4; ++j){
    float mu  = mu_[j]*inv_n;
    float var = s2_[j]*inv_n - mu*mu;
    float sc  = g_[j]*rsqrtf(var + EPSBN);
    float val = fmaxf(0.f, fmaf(v[j] - mu, sc, b_[j]));
    vf[j] = val;
    hb[j] = f2bf(val);
  }
  if (OM == 0){
    *(u16x4*)(ob + i) = hb;
  } else {
    *(f32x4*)(of + i) = vf;
    *(u16x4*)(oh + i) = hb;
  }
}

// ---------------- launch ----------------
extern "C" void kernel_launch(void* const* d_in, const int* in_sizes, int n_in,
                              void* d_out, int out_size, void* d_ws, size_t ws_size,
                              hipStream_t stream){
  const float* h0   = (const float*)d_in[0];
  const float* norm = (const float*)d_in[1];
  const float* V    = (const float*)d_in[2];
  const float* comp = (const float*)d_in[3];
  const float* bias = (const float*)d_in[4];
  const float* W1   = (const float*)d_in[5];
  const float* b1   = (const float*)d_in[6];
  const float* g1   = (const float*)d_in[7];
  const float* bt1  = (const float*)d_in[8];
  const float* W2   = (const float*)d_in[9];
  const float* b2   = (const float*)d_in[10];
  const float* g2   = (const float*)d_in[11];
  const float* bt2  = (const float*)d_in[12];
  const int* src    = (const int*)d_in[13];
  const int* dst    = (const int*)d_in[14];
  const int* et     = (const int*)d_in[15];

  const int N  = in_sizes[0] / DF;     // 20000
  const int E  = in_sizes[13];         // 320000
  const int MT = (N + 127) / 128;      // 157
  const int MP = MT * 128;             // 20096
  const size_t MPDF = (size_t)MP * DF;
  const size_t NDF  = (size_t)N * DF;
  const int NTILES = (E + 127)/128 + RREL;
  float* out = (float*)d_out;

  uint8_t* w = (uint8_t*)d_ws;
  size_t o = 0;
  auto carve = [&](size_t bytes)->void*{
    void* p = w + o;
    o = (o + bytes + 511) & ~(size_t)511;
    return p;
  };
  float*  y       = (float*) carve(MPDF*4);
  ushort* xb      = (ushort*)carve(MPDF*2);
  ushort* xh      = (ushort*)carve(NDF*2);
  ushort* Wt      = (ushort*)carve((size_t)NLAY*RREL*DF*DF*2);
  ushort* W1t     = (ushort*)carve((size_t)NLAY*DF*DF*2);
  ushort* W2t     = (ushort*)carve((size_t)NLAY*DF*DF*2);
  float*  bnacc   = (float*) carve((size_t)NLAY*4*DF*4);
  int*    countsR = (int*)   carve(RREL*4);
  int*    cursorR = (int*)   carve(RREL*4);
  int*    relOff  = (int*)   carve((RREL+1)*4);
  int*    tileOff = (int*)   carve((RREL+1)*4);
  int*    countsD = (int*)   carve((size_t)N*4);
  int*    cursorD = (int*)   carve((size_t)N*4);
  int*    offsD   = (int*)   carve((size_t)(N+1)*4);
  int*    srcR    = (int*)   carve((size_t)E*4);
  int*    posR    = (int*)   carve((size_t)E*4);
  int*    dstPos  = (int*)   carve((size_t)E*4);
  float*  nrmD    = (float*) carve((size_t)E*4);
  ushort* mD      = (ushort*)carve((size_t)E*DF*2);   // 164 MB

  hipMemsetAsync(countsR, 0, RREL*4, stream);
  hipMemsetAsync(cursorR, 0, RREL*4, stream);
  hipMemsetAsync(countsD, 0, (size_t)N*4, stream);
  hipMemsetAsync(cursorD, 0, (size_t)N*4, stream);
  hipMemsetAsync(bnacc, 0, (size_t)NLAY*4*DF*4, stream);

  // dual counting sorts: by relation (GEMM order) and by dst (reduce order)
  k_hist_rel <<<(E+255)/256, 256, 0, stream>>>(et, countsR, E);
  k_hist_dst <<<(E+255)/256, 256, 0, stream>>>(dst, countsD, E);
  k_scan_rel <<<1, 64, 0, stream>>>(countsR, relOff, tileOff);
  k_scan_dst <<<1, 1024, 0, stream>>>(countsD, offsD, N);
  k_place_rel<<<(E+255)/256, 256, 0, stream>>>(et, src, relOff, cursorR, srcR, posR, E);
  k_place_dst<<<(E+255)/256, 256, 0, stream>>>(dst, offsD, cursorD, posR, norm,
                                               dstPos, nrmD, E);

  // reps[0] = h ; xh = bf16(h)
  hipMemcpyAsync(out, h0, NDF*4, hipMemcpyDeviceToDevice, stream);
  k_f2b<<<(int)(NDF/1024), 256, 0, stream>>>(h0, xh);

  // weights
  k_wrel<<<dim3(RREL, DF/32, NLAY), 256, 0, stream>>>(V, comp, Wt);
  k_transpose_bf16<<<dim3(DF/32, DF/32, NLAY), 256, 0, stream>>>(W1, W1t, DF);
  k_transpose_bf16<<<dim3(DF/32, DF/32, NLAY), 256, 0, stream>>>(W2, W2t, DF);

  const float inv_n = 1.f / (float)N;
  for (int l = 0; l < NLAY; ++l){
    float* ms1 = bnacc + (size_t)(l*4 + 0)*DF;
    float* ss1 = bnacc + (size_t)(l*4 + 1)*DF;
    float* ms2 = bnacc + (size_t)(l*4 + 2)*DF;
    float* ss2 = bnacc + (size_t)(l*4 + 3)*DF;

    k_edge_gemm<<<NTILES, 512, 0, stream>>>(xh, Wt + (size_t)l*RREL*DF*DF,
                                            srcR, dstPos, relOff, tileOff, mD);
    k_seg_sum<<<(N+3)/4, 256, 0, stream>>>(mD, nrmD, offsD, bias + (size_t)l*DF, xb, N);

    k_gemm_mlp<<<dim3(MT, 2), 256, 0, stream>>>(xb, W1t + (size_t)l*DF*DF,
                                                b1 + (size_t)l*DF, y, ms1, ss1, N);
    k_bn_apply<0><<<(int)(NDF/1024), 256, 0, stream>>>(
        y, ms1, ss1, g1 + (size_t)l*DF, bt1 + (size_t)l*DF, inv_n, nullptr, xb, nullptr);

    k_gemm_mlp<<<dim3(MT, 2), 256, 0, stream>>>(xb, W2t + (size_t)l*DF*DF,
                                                b2 + (size_t)l*DF, y, ms2, ss2, N);
    k_bn_apply<1><<<(int)(NDF/1024), 256, 0, stream>>>(
        y, ms2, ss2, g2 + (size_t)l*DF, bt2 + (size_t)l*DF, inv_n,
        out + (size_t)(l+1)*NDF, nullptr, xh);
  }
}

// Round 8
// 974.711 us; speedup vs baseline: 1.5046x; 1.0807x over previous
//
#include <hip/hip_runtime.h>
#include <hip/hip_bf16.h>
#include <stdint.h>

#define DF   256
#define NBAS 30
#define RREL 64
#define NLAY 3
#define EPSBN 1e-5f
#define NSLICE 4

typedef short  bf16x8 __attribute__((ext_vector_type(8)));
typedef float  f32x4  __attribute__((ext_vector_type(4)));
typedef ushort u16x4  __attribute__((ext_vector_type(4)));

typedef __attribute__((address_space(1))) const unsigned int gu32;
typedef __attribute__((address_space(3))) unsigned int       lu32;

__device__ __forceinline__ void gload16(const void* g, void* l){
  __builtin_amdgcn_global_load_lds((gu32*)g, (lu32*)l, 16, 0, 0);
}

__device__ __forceinline__ ushort f2bf(float f){
  union { float f; uint32_t u; } v; v.f = f;
  uint32_t r = (v.u + 0x7FFFu + ((v.u >> 16) & 1u)) >> 16;
  return (ushort)r;
}
__device__ __forceinline__ float bf2f(ushort u){
  union { uint32_t u; float f; } v; v.u = (uint32_t)u << 16;
  return v.f;
}

// ---------------- histograms ----------------
__global__ __launch_bounds__(256) void k_hist_rel(const int* __restrict__ et,
                                                  int* __restrict__ counts, int E){
  __shared__ int lh[RREL];
  int t = threadIdx.x;
  if (t < RREL) lh[t] = 0;
  __syncthreads();
  int i = blockIdx.x*256 + t;
  if (i < E) atomicAdd(&lh[et[i]], 1);
  __syncthreads();
  if (t < RREL && lh[t]) atomicAdd(&counts[t], lh[t]);
}

__global__ void k_hist_dst(const int* __restrict__ dst, int* __restrict__ counts, int E){
  int i = blockIdx.x*blockDim.x + threadIdx.x;
  if (i < E) atomicAdd(&counts[dst[i]], 1);
}

// ---------------- scans ----------------
__global__ void k_scan_rel(const int* __restrict__ counts, int* __restrict__ relOff){
  int l = threadIdx.x;          // 64 lanes
  int ic = counts[l];
  #pragma unroll
  for (int o = 1; o < 64; o <<= 1){
    int u = __shfl_up(ic, o); if (l >= o) ic += u;
  }
  if (l == 0) relOff[0] = 0;
  relOff[l+1] = ic;
}

__global__ void k_scan_dst(const int* __restrict__ counts, int* __restrict__ offs, int n){
  __shared__ int tmp[1024];
  __shared__ int carry;
  int t = threadIdx.x;
  if (t == 0) carry = 0;
  __syncthreads();
  for (int s = 0; s < n; s += 1024){
    int i = s + t;
    int v = (i < n) ? counts[i] : 0;
    tmp[t] = v;
    __syncthreads();
    for (int o = 1; o < 1024; o <<= 1){
      int u = (t >= o) ? tmp[t - o] : 0;
      __syncthreads();
      tmp[t] += u;
      __syncthreads();
    }
    int incl = tmp[t];
    int base = carry;
    if (i < n) offs[i] = base + incl - v;
    __syncthreads();
    if (t == 1023) carry = base + incl;
    __syncthreads();
  }
  if (t == 0) offs[n] = carry;
}

// ---------------- placements ----------------
__global__ __launch_bounds__(256) void k_place_rel(const int* __restrict__ et,
    const int* __restrict__ src, const int* __restrict__ relOff,
    int* __restrict__ cursor, int* __restrict__ srcR, int* __restrict__ posR, int E){
  __shared__ int lcnt[RREL];
  __shared__ int lbase[RREL];
  int t = threadIdx.x;
  if (t < RREL) lcnt[t] = 0;
  __syncthreads();
  int i = blockIdx.x*256 + t;
  int r = 0, my = 0;
  bool v = (i < E);
  if (v){ r = et[i]; my = atomicAdd(&lcnt[r], 1); }
  __syncthreads();
  if (t < RREL && lcnt[t]) lbase[t] = atomicAdd(&cursor[t], lcnt[t]);
  __syncthreads();
  if (v){
    int p = relOff[r] + lbase[r] + my;
    srcR[p] = src[i];
    posR[i] = p;
  }
}

__global__ __launch_bounds__(256) void k_place_dst(const int* __restrict__ dst,
    const int* __restrict__ offsD, int* __restrict__ cursorD,
    const int* __restrict__ posR, const float* __restrict__ nrm,
    int* __restrict__ dstPos, float* __restrict__ nrmD, int E){
  int i = blockIdx.x*256 + threadIdx.x;
  if (i < E){
    int d = dst[i];
    int q = offsD[d] + atomicAdd(&cursorD[d], 1);
    dstPos[posR[i]] = q;
    nrmD[q] = nrm[i];
  }
}

// ---------------- W_rel precompute: Wt[l][r][col][k] = bf16(sum_b comp*V) ----------------
__global__ __launch_bounds__(256) void k_wrel(const float* __restrict__ V,
    const float* __restrict__ comp, ushort* __restrict__ Wt){
  const int r  = blockIdx.x;
  const int k0 = blockIdx.y*32;
  const int l  = blockIdx.z;
  const int col = threadIdx.x;
  float acc[32];
  #pragma unroll
  for (int kk = 0; kk < 32; ++kk) acc[kk] = 0.f;
  for (int b = 0; b < NBAS; ++b){
    float cb = comp[(size_t)(l*RREL + r)*NBAS + b];
    const float* Vb = V + (((size_t)(l*NBAS + b)*DF) + k0)*DF + col;
    #pragma unroll
    for (int kk = 0; kk < 32; ++kk) acc[kk] = fmaf(cb, Vb[(size_t)kk*DF], acc[kk]);
  }
  ushort* o = Wt + ((size_t)(l*RREL + r)*DF + col)*DF + k0;
  #pragma unroll
  for (int i4 = 0; i4 < 8; ++i4){
    u16x4 p;
    #pragma unroll
    for (int j = 0; j < 4; ++j) p[j] = f2bf(acc[i4*4 + j]);
    *(u16x4*)(o + i4*4) = p;
  }
}

// ---------------- transpose fp32 [K,256] -> bf16 [256,K], layered via z ----------------
__global__ void k_transpose_bf16(const float* __restrict__ in, ushort* __restrict__ out, int K){
  const float* inz  = in  + (size_t)blockIdx.z*K*DF;
  ushort*      outz = out + (size_t)blockIdx.z*DF*K;
  __shared__ float tile[32][33];
  int k0 = blockIdx.x*32, n0 = blockIdx.y*32;
  int tx = threadIdx.x & 31, ty = threadIdx.x >> 5;
  #pragma unroll
  for (int i = 0; i < 32; i += 8)
    tile[ty+i][tx] = inz[(size_t)(k0+ty+i)*DF + n0 + tx];
  __syncthreads();
  #pragma unroll
  for (int i = 0; i < 32; i += 8)
    outz[(size_t)(n0+ty+i)*K + k0 + tx] = f2bf(tile[tx][ty+i]);
}

// ---------------- fp32 -> bf16 ----------------
__global__ __launch_bounds__(256) void k_f2b(const float* __restrict__ in,
                                             ushort* __restrict__ o){
  size_t i = ((size_t)blockIdx.x*256 + threadIdx.x)*4;
  f32x4 v = *(const f32x4*)(in + i);
  u16x4 p;
  #pragma unroll
  for (int j = 0; j < 4; ++j) p[j] = f2bf(v[j]);
  *(u16x4*)(o + i) = p;
}

// ---------------- persistent-W edge GEMM ----------------
// block = (rel, slice, colhalf). Ws = W_r[colhalf] 64KB resident; loop 64-edge tiles,
// dbuf 8KB A-chunks (BK=64), XOR-swizzled LDS; epilogue via freed A-buffer.
__global__ __launch_bounds__(512) void k_edge_gemm2(
    const ushort* __restrict__ xh, const ushort* __restrict__ Wt,
    const int* __restrict__ srcR, const int* __restrict__ dstPos,
    const int* __restrict__ relOff, ushort* __restrict__ mD){
  __shared__ __align__(16) ushort Ws[128*256];    // 64KB [128 cols][256 k]
  __shared__ __align__(16) ushort AsB[2*64*64];   // 2 x 8KB [64 rows][64 k]
  const int b     = blockIdx.x;
  const int r     = b >> 3;
  const int slice = (b >> 1) & (NSLICE-1);
  const int ch    = b & 1;
  const int e0 = relOff[r], e1 = relOff[r+1];
  const int tiles = (e1 - e0 + 63) >> 6;
  const int t0 = (tiles*slice)/NSLICE, t1 = (tiles*(slice+1))/NSLICE;
  if (t0 >= t1) return;
  const int emax = e1 - 1;
  const int tid  = threadIdx.x;
  const int lane = tid & 63, wid = tid >> 6;
  const int wg = wid >> 2;              // row group 0/1 (32 rows each)
  const int wc = (wid & 3)*32;          // col group base (local 128 cols)
  const int l15 = lane & 15, lhi = lane >> 4;

  // stage Ws once (source-XOR so linear LDS is swizzled)
  const char* Wr = (const char*)(Wt + ((size_t)r*256 + ch*128)*256);
  #pragma unroll
  for (int i = 0; i < 8; ++i){
    int db = (i*512 + tid)*16;
    int col = db >> 9, kb = db & 511;
    gload16(Wr + col*512 + (kb ^ ((col & 7) << 4)), (char*)Ws + db);
  }

  const int srow = tid >> 3;            // staging row 0..63
  const int skb  = (tid & 7)*16;        // staging 16B slot in 128B row
  const int sswz = skb ^ ((srow & 7) << 4);
  auto STAGE = [&](int c){              // c = tile*4 + kt
    int t = c >> 2, kt = c & 3;
    int e = e0 + t*64 + srow; if (e > emax) e = emax;
    gload16((const char*)(xh + (size_t)srcR[e]*256) + kt*128 + sswz,
            (char*)AsB + (c & 1)*8192 + tid*16);
  };

  const f32x4 z = {0.f,0.f,0.f,0.f};
  f32x4 acc[2][2];
  #pragma unroll
  for (int m = 0; m < 2; ++m){ acc[m][0] = z; acc[m][1] = z; }

  const int cEnd = t1*4;
  int c = t0*4;
  STAGE(c);
  __syncthreads();

  for (; c < cEnd; ++c){
    const int kt = c & 3;
    if (c + 1 < cEnd) STAGE(c + 1);
    const char* Ab = (const char*)AsB + (c & 1)*8192;
    #pragma unroll
    for (int ks = 0; ks < 2; ++ks){
      const int kloc  = ks*64 + lhi*16;            // byte in 128B A-row
      const int kbyte = kt*128 + ks*64 + lhi*16;   // byte in 512B W-row
      bf16x8 af[2], bw[2];
      #pragma unroll
      for (int m = 0; m < 2; ++m){
        int row = wg*32 + m*16 + l15;
        af[m] = *(const bf16x8*)(Ab + row*128 + (kloc ^ ((row & 7) << 4)));
      }
      #pragma unroll
      for (int n = 0; n < 2; ++n){
        int col = wc + n*16 + l15;
        bw[n] = *(const bf16x8*)((const char*)Ws + col*512 + (kbyte ^ ((col & 7) << 4)));
      }
      #pragma unroll
      for (int m = 0; m < 2; ++m)
        #pragma unroll
        for (int n = 0; n < 2; ++n)
          acc[m][n] = __builtin_amdgcn_mfma_f32_16x16x32_bf16(af[m], bw[n], acc[m][n], 0, 0, 0);
    }
    __syncthreads();     // next chunk staged; all waves done with Ab

    if (kt == 3){
      // epilogue for tile t = c>>2 through freed buffer AsB[c&1]
      const int t  = c >> 2;
      const int eb = e0 + t*64;
      const int rows = min(64, e1 - eb);
      ushort* epi = (ushort*)((char*)AsB + (c & 1)*8192);   // 8KB: 32 rows x 256B
      #pragma unroll
      for (int h = 0; h < 2; ++h){
        if (wg == h){
          #pragma unroll
          for (int m = 0; m < 2; ++m)
            #pragma unroll
            for (int q = 0; q < 4; ++q){
              int rl = m*16 + lhi*4 + q;            // 0..31 within half
              #pragma unroll
              for (int n = 0; n < 2; ++n){
                int cb = (wc + n*16 + l15)*2;
                *(ushort*)((char*)epi + rl*256 + (cb ^ ((rl & 7) << 5))) = f2bf(acc[m][n][q]);
              }
            }
        }
        __syncthreads();
        int row = tid >> 4;                         // 0..31
        int gr  = h*32 + row;
        if (gr < rows){
          int q = dstPos[eb + gr];
          uint4 v = *(const uint4*)((const char*)epi + row*256 + (((tid & 15)*16) ^ ((row & 7) << 5)));
          *(uint4*)((char*)mD + (size_t)q*512 + ch*256 + (tid & 15)*16) = v;
        }
        __syncthreads();
      }
      #pragma unroll
      for (int m = 0; m < 2; ++m){ acc[m][0] = z; acc[m][1] = z; }
    }
  }
}

// ---------------- segment sum over dst-sorted m + bias -> bf16 xb ----------------
__global__ __launch_bounds__(256) void k_seg_sum(
    const ushort* __restrict__ mD, const float* __restrict__ nrmD,
    const int* __restrict__ offsD, const float* __restrict__ bias,
    ushort* __restrict__ xb, int N){
  const int w = blockIdx.x*4 + (threadIdx.x >> 6);
  if (w >= N) return;
  const int lane = threadIdx.x & 63;
  const int beg = offsD[w], end = offsD[w+1];
  f32x4 a0 = {0.f,0.f,0.f,0.f}, a1 = {0.f,0.f,0.f,0.f};
  const ushort* p = mD + (size_t)beg*DF + lane*4;
  int j = beg;
  for (; j + 4 <= end; j += 4, p += 4*DF){
    u16x4 v0 = *(const u16x4*)(p);
    u16x4 v1 = *(const u16x4*)(p + DF);
    u16x4 v2 = *(const u16x4*)(p + 2*DF);
    u16x4 v3 = *(const u16x4*)(p + 3*DF);
    float n0 = nrmD[j], n1 = nrmD[j+1], n2 = nrmD[j+2], n3 = nrmD[j+3];
    #pragma unroll
    for (int t = 0; t < 4; ++t){
      a0[t] = fmaf(n0, bf2f(v0[t]), a0[t]);
      a1[t] = fmaf(n1, bf2f(v1[t]), a1[t]);
      a0[t] = fmaf(n2, bf2f(v2[t]), a0[t]);
      a1[t] = fmaf(n3, bf2f(v3[t]), a1[t]);
    }
  }
  for (; j < end; ++j, p += DF){
    u16x4 v0 = *(const u16x4*)(p);
    float n0 = nrmD[j];
    #pragma unroll
    for (int t = 0; t < 4; ++t) a0[t] = fmaf(n0, bf2f(v0[t]), a0[t]);
  }
  f32x4 bv = *(const f32x4*)(bias + lane*4);
  u16x4 o;
  #pragma unroll
  for (int t = 0; t < 4; ++t) o[t] = f2bf(a0[t] + a1[t] + bv[t]);
  *(u16x4*)(xb + (size_t)w*DF + lane*4) = o;
}

// ---------------- MLP GEMM 64x128 (K=256): y = A @ Bt + bias, fused BN stats ----------------
__global__ __launch_bounds__(256) void k_gemm_mlp(
    const ushort* __restrict__ A, const ushort* __restrict__ Bt,
    const float* __restrict__ bias, float* __restrict__ out,
    float* __restrict__ msum, float* __restrict__ ssum, int a_valid){
  __shared__ __align__(16) ushort As[64*64];    // 8KB  swizzled
  __shared__ __align__(16) ushort Bs[128*64];   // 16KB swizzled
  const int tid  = threadIdx.x;
  const int brow = blockIdx.x*64;
  const int bcol = blockIdx.y*128;
  const int lane = tid & 63, wid = tid >> 6;
  const int wr = (wid >> 1)*32, wc = (wid & 1)*64;
  const int l15 = lane & 15, lhi = lane >> 4;

  const f32x4 z = {0.f,0.f,0.f,0.f};
  f32x4 acc[2][4];
  #pragma unroll
  for (int m = 0; m < 2; ++m)
    #pragma unroll
    for (int n = 0; n < 4; ++n) acc[m][n] = z;

  for (int kt = 0; kt < 4; ++kt){
    __syncthreads();
    #pragma unroll
    for (int i = 0; i < 2; ++i){
      int p = tid + i*256;
      int row = p >> 3, kb = (p & 7)*16;
      int ra = brow + row; if (ra >= a_valid) ra = a_valid - 1;
      gload16((const char*)(A + (size_t)ra*DF) + kt*128 + (kb ^ ((row & 7) << 4)),
              (char*)As + p*16);
    }
    #pragma unroll
    for (int i = 0; i < 4; ++i){
      int p = tid + i*256;
      int col = p >> 3, kb = (p & 7)*16;
      gload16((const char*)(Bt + (size_t)(bcol + col)*DF) + kt*128 + (kb ^ ((col & 7) << 4)),
              (char*)Bs + p*16);
    }
    __syncthreads();
    #pragma unroll
    for (int ks = 0; ks < 2; ++ks){
      const int kloc = ks*64 + lhi*16;
      bf16x8 af[2], bf_[4];
      #pragma unroll
      for (int m = 0; m < 2; ++m){
        int row = wr + m*16 + l15;
        af[m] = *(const bf16x8*)((const char*)As + row*128 + (kloc ^ ((row & 7) << 4)));
      }
      #pragma unroll
      for (int n = 0; n < 4; ++n){
        int col = wc + n*16 + l15;
        bf_[n] = *(const bf16x8*)((const char*)Bs + col*128 + (kloc ^ ((col & 7) << 4)));
      }
      #pragma unroll
      for (int m = 0; m < 2; ++m)
        #pragma unroll
        for (int n = 0; n < 4; ++n)
          acc[m][n] = __builtin_amdgcn_mfma_f32_16x16x32_bf16(af[m], bf_[n], acc[m][n], 0, 0, 0);
    }
  }

  #pragma unroll
  for (int n = 0; n < 4; ++n){
    const int col = bcol + wc + n*16 + l15;
    const float bv = bias[col];
    float s = 0.f, s2 = 0.f;
    #pragma unroll
    for (int m = 0; m < 2; ++m){
      #pragma unroll
      for (int q = 0; q < 4; ++q){
        int grow = brow + wr + m*16 + lhi*4 + q;
        float v  = acc[m][n][q] + bv;
        out[(size_t)grow*DF + col] = v;
        if (grow < a_valid){ s += v; s2 = fmaf(v, v, s2); }
      }
    }
    s  += __shfl_xor(s, 16);  s  += __shfl_xor(s, 32);
    s2 += __shfl_xor(s2, 16); s2 += __shfl_xor(s2, 32);
    if (lhi == 0){ atomicAdd(&msum[col], s); atomicAdd(&ssum[col], s2); }
  }
}

// ---------------- BN apply + ReLU ----------------
template<int OM>
__global__ __launch_bounds__(256) void k_bn_apply(const float* __restrict__ y,
    const float* __restrict__ msum, const float* __restrict__ ssum,
    const float* __restrict__ g, const float* __restrict__ bt,
    float inv_n, float* __restrict__ of, ushort* __restrict__ ob,
    ushort* __restrict__ oh){
  size_t i = ((size_t)blockIdx.x*256 + threadIdx.x)*4;
  int col = (int)(i & (DF-1));
  f32x4 v   = *(const f32x4*)(y + i);
  f32x4 mu_ = *(const f32x4*)(msum + col);
  f32x4 s2_ = *(const f32x4*)(ssum + col);
  f32x4 g_  = *(const f32x4*)(g + col);
  f32x4 b_  = *(const f32x4*)(bt + col);
  u16x4 hb; f32x4 vf;
  #pragma unroll
  for (int j = 0; j < 4; ++j){
    float mu  = mu_[j]*inv_n;
    float var = s2_[j]*inv_n - mu*mu;
    float sc  = g_[j]*rsqrtf(var + EPSBN);
    float val = fmaxf(0.f, fmaf(v[j] - mu, sc, b_[j]));
    vf[j] = val;
    hb[j] = f2bf(val);
  }
  if (OM == 0){
    *(u16x4*)(ob + i) = hb;
  } else {
    *(f32x4*)(of + i) = vf;
    *(u16x4*)(oh + i) = hb;
  }
}

// ---------------- launch ----------------
extern "C" void kernel_launch(void* const* d_in, const int* in_sizes, int n_in,
                              void* d_out, int out_size, void* d_ws, size_t ws_size,
                              hipStream_t stream){
  const float* h0   = (const float*)d_in[0];
  const float* norm = (const float*)d_in[1];
  const float* V    = (const float*)d_in[2];
  const float* comp = (const float*)d_in[3];
  const float* bias = (const float*)d_in[4];
  const float* W1   = (const float*)d_in[5];
  const float* b1   = (const float*)d_in[6];
  const float* g1   = (const float*)d_in[7];
  const float* bt1  = (const float*)d_in[8];
  const float* W2   = (const float*)d_in[9];
  const float* b2   = (const float*)d_in[10];
  const float* g2   = (const float*)d_in[11];
  const float* bt2  = (const float*)d_in[12];
  const int* src    = (const int*)d_in[13];
  const int* dst    = (const int*)d_in[14];
  const int* et     = (const int*)d_in[15];

  const int N  = in_sizes[0] / DF;     // 20000
  const int E  = in_sizes[13];         // 320000
  const int MP = ((N + 127)/128)*128;  // 20096
  const size_t MPDF = (size_t)MP * DF;
  const size_t NDF  = (size_t)N * DF;
  float* out = (float*)d_out;

  uint8_t* w = (uint8_t*)d_ws;
  size_t o = 0;
  auto carve = [&](size_t bytes)->void*{
    void* p = w + o;
    o = (o + bytes + 511) & ~(size_t)511;
    return p;
  };
  float*  y       = (float*) carve(MPDF*4);
  ushort* xb      = (ushort*)carve(MPDF*2);
  ushort* xh      = (ushort*)carve(NDF*2);
  ushort* Wt      = (ushort*)carve((size_t)NLAY*RREL*DF*DF*2);
  ushort* W1t     = (ushort*)carve((size_t)NLAY*DF*DF*2);
  ushort* W2t     = (ushort*)carve((size_t)NLAY*DF*DF*2);
  float*  bnacc   = (float*) carve((size_t)NLAY*4*DF*4);
  int*    countsR = (int*)   carve(RREL*4);
  int*    cursorR = (int*)   carve(RREL*4);
  int*    relOff  = (int*)   carve((RREL+1)*4);
  int*    countsD = (int*)   carve((size_t)N*4);
  int*    cursorD = (int*)   carve((size_t)N*4);
  int*    offsD   = (int*)   carve((size_t)(N+1)*4);
  int*    srcR    = (int*)   carve((size_t)E*4);
  int*    posR    = (int*)   carve((size_t)E*4);
  int*    dstPos  = (int*)   carve((size_t)E*4);
  float*  nrmD    = (float*) carve((size_t)E*4);
  ushort* mD      = (ushort*)carve((size_t)E*DF*2);   // 164 MB

  hipMemsetAsync(countsR, 0, RREL*4, stream);
  hipMemsetAsync(cursorR, 0, RREL*4, stream);
  hipMemsetAsync(countsD, 0, (size_t)N*4, stream);
  hipMemsetAsync(cursorD, 0, (size_t)N*4, stream);
  hipMemsetAsync(bnacc, 0, (size_t)NLAY*4*DF*4, stream);

  // dual counting sorts: by relation (GEMM order) and by dst (reduce order)
  k_hist_rel <<<(E+255)/256, 256, 0, stream>>>(et, countsR, E);
  k_hist_dst <<<(E+255)/256, 256, 0, stream>>>(dst, countsD, E);
  k_scan_rel <<<1, 64, 0, stream>>>(countsR, relOff);
  k_scan_dst <<<1, 1024, 0, stream>>>(countsD, offsD, N);
  k_place_rel<<<(E+255)/256, 256, 0, stream>>>(et, src, relOff, cursorR, srcR, posR, E);
  k_place_dst<<<(E+255)/256, 256, 0, stream>>>(dst, offsD, cursorD, posR, norm,
                                               dstPos, nrmD, E);

  // reps[0] = h ; xh = bf16(h)
  hipMemcpyAsync(out, h0, NDF*4, hipMemcpyDeviceToDevice, stream);
  k_f2b<<<(int)(NDF/1024), 256, 0, stream>>>(h0, xh);

  // weights
  k_wrel<<<dim3(RREL, DF/32, NLAY), 256, 0, stream>>>(V, comp, Wt);
  k_transpose_bf16<<<dim3(DF/32, DF/32, NLAY), 256, 0, stream>>>(W1, W1t, DF);
  k_transpose_bf16<<<dim3(DF/32, DF/32, NLAY), 256, 0, stream>>>(W2, W2t, DF);

  const float inv_n = 1.f / (float)N;
  const int MT2 = (N + 63)/64;   // 313
  for (int l = 0; l < NLAY; ++l){
    float* ms1 = bnacc + (size_t)(l*4 + 0)*DF;
    float* ss1 = bnacc + (size_t)(l*4 + 1)*DF;
    float* ms2 = bnacc + (size_t)(l*4 + 2)*DF;
    float* ss2 = bnacc + (size_t)(l*4 + 3)*DF;

    k_edge_gemm2<<<RREL*NSLICE*2, 512, 0, stream>>>(xh, Wt + (size_t)l*RREL*DF*DF,
                                                    srcR, dstPos, relOff, mD);
    k_seg_sum<<<(N+3)/4, 256, 0, stream>>>(mD, nrmD, offsD, bias + (size_t)l*DF, xb, N);

    k_gemm_mlp<<<dim3(MT2, 2), 256, 0, stream>>>(xb, W1t + (size_t)l*DF*DF,
                                                 b1 + (size_t)l*DF, y, ms1, ss1, N);
    k_bn_apply<0><<<(int)(NDF/1024), 256, 0, stream>>>(
        y, ms1, ss1, g1 + (size_t)l*DF, bt1 + (size_t)l*DF, inv_n, nullptr, xb, nullptr);

    k_gemm_mlp<<<dim3(MT2, 2), 256, 0, stream>>>(xb, W2t + (size_t)l*DF*DF,
                                                 b2 + (size_t)l*DF, y, ms2, ss2, N);
    k_bn_apply<1><<<(int)(NDF/1024), 256, 0, stream>>>(
        y, ms2, ss2, g2 + (size_t)l*DF, bt2 + (size_t)l*DF, inv_n,
        out + (size_t)(l+1)*NDF, nullptr, xh);
  }
}